// Round 7
// baseline (209.659 us; speedup 1.0000x reference)
//
#include <hip/hip_runtime.h>
#include <hip/hip_bf16.h>

#define Bb 2
#define Tt 2048
#define Cc 1024
#define Hh 16
#define Dd 64

typedef __bf16 bf8 __attribute__((ext_vector_type(8)));
typedef __bf16 bf4 __attribute__((ext_vector_type(4)));
typedef float f4 __attribute__((ext_vector_type(4)));

typedef __attribute__((address_space(3))) void lds_void;
typedef const __attribute__((address_space(1))) void g_void;

__device__ __forceinline__ void gload_lds16(const __bf16* g, __bf16* l) {
  __builtin_amdgcn_global_load_lds((g_void*)g, (lds_void*)l, 16, 0, 0);
}

// exp2 that lowers directly to v_exp_f32 (hw exp is base-2)
__device__ __forceinline__ float ex2(float x) { return __builtin_amdgcn_exp2f(x); }

// fused fp32 -> bf16 convert for x, W_qkv, W_proj in one launch
__global__ __launch_bounds__(256) void cvt3_kernel(
    const float* __restrict__ a, __bf16* __restrict__ oa, int na,
    const float* __restrict__ b, __bf16* __restrict__ ob, int nb,
    const float* __restrict__ c, __bf16* __restrict__ oc) {
  int gi = blockIdx.x * 256 + threadIdx.x;
  const int t0 = na >> 3, t1 = t0 + (nb >> 3);
  const float* src; __bf16* dst; int idx;
  if (gi < t0)      { src = a; dst = oa; idx = gi; }
  else if (gi < t1) { src = b; dst = ob; idx = gi - t0; }
  else              { src = c; dst = oc; idx = gi - t1; }
  const float* p = src + (size_t)idx * 8;
  float4 u = *(const float4*)p;
  float4 v = *(const float4*)(p + 4);
  bf8 r;
  r[0] = (__bf16)u.x; r[1] = (__bf16)u.y; r[2] = (__bf16)u.z; r[3] = (__bf16)u.w;
  r[4] = (__bf16)v.x; r[5] = (__bf16)v.y; r[6] = (__bf16)v.z; r[7] = (__bf16)v.w;
  *(bf8*)(dst + (size_t)idx * 8) = r;
}

// C(M,N) = A(M,K) @ W(N,K)^T + bias.  Double-buffered LDS (attn-style ring:
// barrier -> issue DMA(k+1) -> compute(k), so the vmcnt drain at the NEXT
// barrier is covered by a full compute iteration).  16B-granule XOR swizzle
// g = lq ^ ((row>>1)&3) makes every 8-lane phase of the b128 fragment reads
// cover all 32 banks exactly once (row stride is 64 B).
// MODE 0 (BM=128): scatter q/k (B,H,T,D) + v transposed (B,H,D,T), bf16;
//                  q pre-scaled by 0.125*log2e.
// MODE 1 (BM=64):  fp32 out (leading dim ldo) + bias.  K must be mult of 64.
template<int BM, int BN, int MODE>
__global__ __launch_bounds__(256) void gemm_kernel(
    const __bf16* __restrict__ A, const __bf16* __restrict__ W,
    const float* __restrict__ bias, int K,
    __bf16* __restrict__ q_ws, __bf16* __restrict__ k_ws,
    __bf16* __restrict__ v_ws, float* __restrict__ out, int ldo)
{
  constexpr int WM = (BM == 128) ? 64 : 32;
  constexpr int WN = 64;
  constexpr int WAVES_M = BM / WM;           // 2
  constexpr int MI = WM / 16, NI = WN / 16;
  constexpr int NA = BM / 64, NB = BN / 64;  // 16B chunks per thread per tensor

  const int tid = threadIdx.x;
  const int lane = tid & 63, wave = tid >> 6;
  const int lr = lane & 15, lq = lane >> 4;
  const int m_blk = blockIdx.y * BM, n_blk = blockIdx.x * BN;
  const int wm = (wave % WAVES_M) * WM, wn = (wave / WAVES_M) * WN;

  __shared__ __align__(16) __bf16 As[2][BM * 32];
  __shared__ __align__(16) __bf16 Bs[2][BN * 32];

  // slot s: row=s>>2, pos=s&3 holds global granule c = pos ^ ((row>>1)&3)
  const int scol = ((tid & 3) ^ ((tid >> 3) & 3)) * 8;
  const __bf16* agp[NA];
  const __bf16* bgp[NB];
  #pragma unroll
  for (int i = 0; i < NA; ++i)
    agp[i] = A + (size_t)(m_blk + i * 64 + (tid >> 2)) * K + scol;
  #pragma unroll
  for (int i = 0; i < NB; ++i)
    bgp[i] = W + (size_t)(n_blk + i * 64 + (tid >> 2)) * K + scol;

  const int nk = K >> 5;

  auto stage = [&](int k, int bsel) {
    #pragma unroll
    for (int i = 0; i < NA; ++i)
      gload_lds16(agp[i] + k * 32, &As[bsel][i * 2048 + tid * 8]);
    #pragma unroll
    for (int i = 0; i < NB; ++i)
      gload_lds16(bgp[i] + k * 32, &Bs[bsel][i * 2048 + tid * 8]);
  };

  f4 acc[MI][NI] = {};
  const int xsw = (lr >> 1) & 3;   // (row>>1)&3 for all fragment rows

  auto compute = [&](const __bf16* Ab, const __bf16* Bw) {
    bf8 af[MI], bfr[NI];
    #pragma unroll
    for (int i = 0; i < MI; ++i)
      af[i] = *(const bf8*)&Ab[(wm + i * 16 + lr) * 32 + ((lq ^ xsw) * 8)];
    #pragma unroll
    for (int j = 0; j < NI; ++j)
      bfr[j] = *(const bf8*)&Bw[(wn + j * 16 + lr) * 32 + ((lq ^ xsw) * 8)];
    #pragma unroll
    for (int i = 0; i < MI; ++i)
      #pragma unroll
      for (int j = 0; j < NI; ++j)
        acc[i][j] = __builtin_amdgcn_mfma_f32_16x16x32_bf16(af[i], bfr[j], acc[i][j], 0, 0, 0);
  };

  stage(0, 0);
  for (int k = 0; k + 2 <= nk; k += 2) {   // nk even (K mult of 64)
    __syncthreads();                       // drains DMA(k); buf1 readers done
    if (k + 1 < nk) stage(k + 1, 1);
    compute(As[0], Bs[0]);
    __syncthreads();                       // drains DMA(k+1); buf0 readers done
    if (k + 2 < nk) stage(k + 2, 0);
    compute(As[1], Bs[1]);
  }

  #pragma unroll
  for (int i = 0; i < MI; ++i) {
    #pragma unroll
    for (int j = 0; j < NI; ++j) {
      #pragma unroll
      for (int r = 0; r < 4; ++r) {
        int row = m_blk + wm + i * 16 + lq * 4 + r;  // C/D: row = 4*quad + reg
        int col = n_blk + wn + j * 16 + lr;          // C/D: col = lane&15
        float val = acc[i][j][r] + bias[col];
        if constexpr (MODE == 0) {
          int which = col >> 10, rr = col & 1023;
          int h = rr >> 6, d = rr & 63;
          int b = row >> 11, t = row & 2047;
          if (which == 0) val *= 0.18033688011112042f;  // 1/sqrt(D) * log2(e)
          __bf16 bv = (__bf16)val;
          size_t bh = (size_t)b * Hh + h;
          if (which == 0)      q_ws[(bh * Tt + t) * Dd + d] = bv;
          else if (which == 1) k_ws[(bh * Tt + t) * Dd + d] = bv;
          else                 v_ws[(bh * Dd + d) * Tt + t] = bv;
        } else {
          out[(size_t)row * ldo + col] = val;
        }
      }
    }
  }
}

// Flash attention with sink, fixed softmax reference m=0, log2-domain scores
// (q pre-scaled by 0.125*log2e -> exp is a bare v_exp_f32). S computed
// TRANSPOSED (A=K, B=Q); P spills as b64, reads back as b128 A-frags.
// Software pipeline: triple-buffered K/V ring; during iter kt the wave
// computes S(kt+1) (K-tile already drained at this barrier) so S-MFMA(kt+1)
// co-issues with the exp-VALU(kt) block -> MFMA/VALU overlap within a wave.
// Grid: 512 blocks; i and i+256 have qt summing to 15 (balanced pairs).
__global__ __launch_bounds__(256) void attn_kernel(
    const __bf16* __restrict__ q_ws, const __bf16* __restrict__ k_ws,
    const __bf16* __restrict__ v_ws, const float* __restrict__ sink,
    __bf16* __restrict__ y_ws)
{
  int bi = blockIdx.x;
  int qt, bhi;
  if (bi < 256) { qt = 15 - (bi >> 5); bhi = bi & 31; }
  else          { qt = (bi - 256) >> 5; bhi = (bi - 256) & 31; }
  const int h = bhi & (Hh - 1);
  const int b = bhi >> 4;
  const int tid = threadIdx.x;
  const int lane = tid & 63, wave = tid >> 6;
  const int lr = lane & 15, lq = lane >> 4;

  __shared__ __align__(16) __bf16 KsU[3][64 * 64];     // swizzled [key][d], ring
  __shared__ __align__(16) __bf16 VtU[3][64 * 64];     // swizzled [d][key], ring
  __shared__ __align__(16) __bf16 PsU[4][2 * 16 * 64]; // per-wave [qs][q][key]

  const __bf16* qp = q_ws + (size_t)bhi * Tt * Dd;
  const __bf16* kp = k_ws + (size_t)bhi * Tt * Dd;
  const __bf16* vp = v_ws + (size_t)bhi * Dd * Tt;     // [d][t]

  const int qbase = qt * 128;
  const int qlo = qbase + wave * 32;                   // wave's lowest q row

  // Q fragments: 2 subsets of 16 rows/wave, loop-invariant registers
  bf8 qf[2][2];
  #pragma unroll
  for (int qs = 0; qs < 2; ++qs) {
    const __bf16* qrow = qp + (size_t)(qlo + qs * 16 + lr) * Dd;
    qf[qs][0] = *(const bf8*)(qrow + lq * 8);
    qf[qs][1] = *(const bf8*)(qrow + 32 + lq * 8);
  }

  float rs[2] = {0.f, 0.f};   // per-lane denominator partial (q = lr, per subset)
  f4 o_acc[2][4] = {};

  const int srow_lo = wave * 8 + (lane >> 3);
  const int sslot = lane & 7;
  const int nkt = 2 * qt + 2;

  auto stage = [&](int kt2, int bsel) {
    const int kbase2 = kt2 * 64;
    #pragma unroll
    for (int ii = 0; ii < 2; ++ii) {
      const int r = ii * 32 + srow_lo;
      const int cc = sslot ^ (r & 7);            // XOR granule swizzle
      gload_lds16(kp + (size_t)(kbase2 + r) * Dd + cc * 8,
                  &KsU[bsel][ii * 2048 + wave * 512 + lane * 8]);
      gload_lds16(vp + (size_t)r * Tt + kbase2 + cc * 8,
                  &VtU[bsel][ii * 2048 + wave * 512 + lane * 8]);
    }
  };

  auto computeS = [&](const __bf16* Kb, f4 (&sA)[4][2]) {
    #pragma unroll
    for (int nt = 0; nt < 4; ++nt) {
      const int krow = nt * 16 + lr;
      const int x7 = krow & 7;
      bf8 kb0 = *(const bf8*)&Kb[krow * 64 + ((lq ^ x7) * 8)];
      bf8 kb1 = *(const bf8*)&Kb[krow * 64 + (((4 + lq) ^ x7) * 8)];
      #pragma unroll
      for (int qs = 0; qs < 2; ++qs) {
        f4 c = {};
        c = __builtin_amdgcn_mfma_f32_16x16x32_bf16(kb0, qf[qs][0], c, 0, 0, 0);
        c = __builtin_amdgcn_mfma_f32_16x16x32_bf16(kb1, qf[qs][1], c, 0, 0, 0);
        sA[nt][qs] = c;
      }
    }
  };

  f4 s_cur[4][2], s_next[4][2];

  stage(0, 0);
  __syncthreads();          // drain DMA(0)
  stage(1, 1);              // drains at first loop barrier
  computeS(KsU[0], s_cur);

  for (int kt = 0; kt < nkt; ++kt) {
    __syncthreads();        // drains DMA(kt+1); syncs ring reuse
    if (kt + 2 < nkt) stage(kt + 2, (kt + 2) % 3);

    // prefetch S for next tile — independent of exp/PV below (MFMA ∥ VALU)
    if (kt + 1 < nkt && (kt + 1) * 64 <= qlo + 31)
      computeS(KsU[(kt + 1) % 3], s_next);

    const int kbase = kt * 64;
    if (kbase <= qlo + 31) {
      __bf16* Pw = PsU[wave];
      const bool diag = (kbase + 63 > qlo);   // wave-uniform
      if (diag) {
        #pragma unroll
        for (int nt = 0; nt < 4; ++nt)
          #pragma unroll
          for (int qs = 0; qs < 2; ++qs) {
            const int qg = qlo + qs * 16 + lr;
            const int kg = kbase + nt * 16 + lq * 4;
            bf4 pb;
            #pragma unroll
            for (int r = 0; r < 4; ++r) {
              float sv = (kg + r > qg) ? -1e30f : s_cur[nt][qs][r];
              float p = ex2(sv);              // scores already in log2 domain
              rs[qs] += p;
              pb[r] = (__bf16)p;
            }
            const int G = (nt * 2 + (lq >> 1)) ^ (lr & 7);
            *(bf4*)&Pw[(qs * 16 + lr) * 64 + G * 8 + (lq & 1) * 4] = pb;
          }
      } else {
        #pragma unroll
        for (int nt = 0; nt < 4; ++nt)
          #pragma unroll
          for (int qs = 0; qs < 2; ++qs) {
            bf4 pb;
            #pragma unroll
            for (int r = 0; r < 4; ++r) {
              float p = ex2(s_cur[nt][qs][r]);
              rs[qs] += p;
              pb[r] = (__bf16)p;
            }
            const int G = (nt * 2 + (lq >> 1)) ^ (lr & 7);
            *(bf4*)&Pw[(qs * 16 + lr) * 64 + G * 8 + (lq & 1) * 4] = pb;
          }
      }
      asm volatile("s_waitcnt lgkmcnt(0)" ::: "memory");  // wave-private RAW on Pw

      const __bf16* Vb = VtU[kt % 3];
      #pragma unroll
      for (int ks = 0; ks < 2; ++ks) {
        const int pg = ((ks * 4 + lq) ^ (lr & 7)) * 8;
        bf8 pa0 = *(const bf8*)&Pw[lr * 64 + pg];
        bf8 pa1 = *(const bf8*)&Pw[(16 + lr) * 64 + pg];
        #pragma unroll
        for (int dt = 0; dt < 4; ++dt) {
          const int vrow = dt * 16 + lr;
          bf8 vb = *(const bf8*)&Vb[vrow * 64 + (((ks * 4 + lq) ^ (vrow & 7)) * 8)];
          o_acc[0][dt] = __builtin_amdgcn_mfma_f32_16x16x32_bf16(pa0, vb, o_acc[0][dt], 0, 0, 0);
          o_acc[1][dt] = __builtin_amdgcn_mfma_f32_16x16x32_bf16(pa1, vb, o_acc[1][dt], 0, 0, 0);
        }
      }
    }

    #pragma unroll
    for (int nt = 0; nt < 4; ++nt)
      #pragma unroll
      for (int qs = 0; qs < 2; ++qs)
        s_cur[nt][qs] = s_next[nt][qs];
  }

  // denominator: reduce per-lane partials over lq (lanes sharing lr)
  #pragma unroll
  for (int qs = 0; qs < 2; ++qs) {
    rs[qs] += __shfl_xor(rs[qs], 16, 64);
    rs[qs] += __shfl_xor(rs[qs], 32, 64);
  }
  const float snk = ex2(sink[h] * 1.44269504f);   // e^sink
  float inv0 = 1.0f / (rs[0] + snk);
  float inv1 = 1.0f / (rs[1] + snk);
  // redistribute: O rows are q = lq*4+r; denom lives at lane with lr == lq*4+r
  float invr[2][4];
  #pragma unroll
  for (int r = 0; r < 4; ++r) {
    invr[0][r] = __shfl(inv0, lq * 4 + r, 64);
    invr[1][r] = __shfl(inv1, lq * 4 + r, 64);
  }

  #pragma unroll
  for (int qs = 0; qs < 2; ++qs)
    #pragma unroll
    for (int dt = 0; dt < 4; ++dt)
      #pragma unroll
      for (int r = 0; r < 4; ++r) {
        int qrow = qbase + wave * 32 + qs * 16 + lq * 4 + r;
        y_ws[((size_t)b * Tt + qrow) * Cc + h * Dd + dt * 16 + lr] =
            (__bf16)(o_acc[qs][dt][r] * invr[qs][r]);
      }
}

extern "C" void kernel_launch(void* const* d_in, const int* in_sizes, int n_in,
                              void* d_out, int out_size, void* d_ws, size_t ws_size,
                              hipStream_t stream) {
  const float* x      = (const float*)d_in[0];
  const float* W_qkv  = (const float*)d_in[1];
  const float* b_qkv  = (const float*)d_in[2];
  const float* W_proj = (const float*)d_in[3];
  const float* b_proj = (const float*)d_in[4];
  const float* sinkp  = (const float*)d_in[5];
  float* out = (float*)d_out;

  const size_t n_x    = (size_t)Bb * Tt * Cc;        // 4.19M
  const size_t n_wqkv = (size_t)3 * Hh * Dd * Cc;    // 3.15M
  const size_t n_wprj = (size_t)Cc * Hh * Dd;        // 1.05M
  const size_t nqkv   = (size_t)Bb * Hh * Tt * Dd;   // 4.19M

  __bf16* xb     = (__bf16*)d_ws;          // also aliased as y_ws after QKV GEMM
  __bf16* wqkvb  = xb + n_x;
  __bf16* wprojb = wqkvb + n_wqkv;
  __bf16* q_ws   = wprojb + n_wprj;
  __bf16* k_ws   = q_ws + nqkv;
  __bf16* v_ws   = k_ws + nqkv;
  __bf16* y_ws   = xb;                     // lifetime-disjoint alias

  dim3 blk(256);
  const int cvt_blocks = (int)((n_x + n_wqkv + n_wprj) / 8 / 256);  // 4096
  cvt3_kernel<<<cvt_blocks, blk, 0, stream>>>(x, xb, (int)n_x,
                                              W_qkv, wqkvb, (int)n_wqkv,
                                              W_proj, wprojb);

  // QKV: M=4096, N=3072, K=1024 — 768 blocks (3/CU)
  gemm_kernel<128, 128, 0><<<dim3(3 * Cc / 128, Bb * Tt / 128), blk, 0, stream>>>(
      xb, wqkvb, b_qkv, Cc, q_ws, k_ws, v_ws, nullptr, 0);
  // attention: 512 balanced-pair blocks (2/CU)
  attn_kernel<<<dim3(512), blk, 0, stream>>>(q_ws, k_ws, v_ws, sinkp, y_ws);
  // proj: M=4096, N=1024, K=1024 — 64-row tiles -> 512 blocks (2/CU)
  gemm_kernel<64, 128, 1><<<dim3(Cc / 128, Bb * Tt / 64), blk, 0, stream>>>(
      y_ws, wprojb, b_proj, Hh * Dd, nullptr, nullptr, nullptr, out, Cc);
}